// Round 1
// 1576.772 us; speedup vs baseline: 2.4922x; 2.4922x over previous
//
#include <hip/hip_runtime.h>
#include <math.h>

// Problem constants
#define B_ 8
#define T_ 50
#define N_ 1000
#define F_ 4
#define G_ 32
#define H_ 256
#define E_ 32000
#define S_ 5
#define R_ 400        // B*T
#define K0_ 32000     // N*G (LSTM0 input size)
#define NG_ 1024      // 4*H
#define KS_ 16        // split-K factor for big GEMM
#define KRANGE_ 2000  // K0_/KS_

static __device__ __forceinline__ float sigm(float x) { return 1.0f / (1.0f + expf(-x)); }

// ---------------------------------------------------------------------------
// Kernel 1a: GCN scatter, reassociated as (A @ X) @ W instead of A @ (X @ W).
// Scatter the RAW F=4 features per edge -> 8x fewer LDS atomic lane-ops
// (51.2M vs 409.6M) and 32x fewer LDS gather bytes. 2 WGs per (b,t), each
// owning half the edge list with a private 16KB aggX; partials merged in 1b.
// 512 thr, 32KB LDS -> 4 WGs/CU, all 800 WGs resident in one round.
// ---------------------------------------------------------------------------
__global__ __launch_bounds__(512, 8) void gcn_scatter(
    const float* __restrict__ x, const int* __restrict__ ei,
    const float* __restrict__ ew, float* __restrict__ P) {
  __shared__ float xs[N_ * 4];      // 16 KB (x[n][0..3])
  __shared__ float aggX[N_ * 4];    // 16 KB (partial A@X, this WG's edge half)
  const int r = blockIdx.x >> 1;
  const int eh = blockIdx.x & 1;    // edge half: [eh*16000, eh*16000+16000)
  const int tid = threadIdx.x;

  // stage x row-block (coalesced float4)
  const float4* xg = (const float4*)(x + (size_t)r * N_ * F_);
  float4* xs4 = (float4*)xs;
  for (int i = tid; i < N_; i += 512) xs4[i] = xg[i];
  float4* av = (float4*)aggX;
  for (int i = tid; i < N_; i += 512) av[i] = make_float4(0.f, 0.f, 0.f, 0.f);
  __syncthreads();

  const int* src = ei + (size_t)r * 2 * E_;
  const int* dst = src + E_;
  const float* wp = ew + (size_t)r * E_;

  // wave = 16 edge-slots x 4 features; 125 iterations exactly
  const int f = tid & 3;
  const int es = tid >> 2;          // 0..127
  const int e0 = eh * (E_ / 2);
  const int e1 = e0 + (E_ / 2);
  for (int e = e0 + es; e < e1; e += 128) {
    const int s = src[e], d = dst[e];
    const float m = wp[e] * xs[(s << 2) | f];
    unsafeAtomicAdd(&aggX[(d << 2) | f], m);
  }
  __syncthreads();

  // dump partial to global (reuses the 'part' region; gemm_ih overwrites later)
  float4* pv = (float4*)(P + (size_t)blockIdx.x * (N_ * 4));
  for (int i = tid; i < N_; i += 512) pv[i] = av[i];
}

// ---------------------------------------------------------------------------
// Kernel 1b: merge the two edge-half partials, apply the dense F->G transform
// + bias + tanh:  z[r][n*32+g] = tanh(b[g] + sum_f aggX[n][f] * W[f][g])
// 102 MFLOP total + ~64 MB traffic -> trivial.
// ---------------------------------------------------------------------------
__global__ __launch_bounds__(256) void gcn_transform(
    const float* __restrict__ P, const float* __restrict__ Wg,
    const float* __restrict__ bg, float* __restrict__ Z) {
  __shared__ float mm[N_ * 4];      // merged aggX for this r
  const int r = blockIdx.x;
  const int tid = threadIdx.x;
  const float* P0 = P + (size_t)(2 * r) * (N_ * 4);
  const float* P1 = P0 + N_ * 4;
  for (int i = tid; i < N_ * 4; i += 256) mm[i] = P0[i] + P1[i];
  const int g = tid & 31;           // fixed per thread (256 % 32 == 0)
  const float w0 = Wg[0 * G_ + g], w1 = Wg[1 * G_ + g];
  const float w2 = Wg[2 * G_ + g], w3 = Wg[3 * G_ + g];
  const float bv = bg[g];
  __syncthreads();
  float* Zr = Z + (size_t)r * K0_;
  for (int i = tid; i < K0_; i += 256) {
    const int n = i >> 5;
    const float4 a = *(const float4*)&mm[n << 2];   // broadcast within group
    Zr[i] = tanhf(bv + a.x * w0 + a.y * w1 + a.z * w2 + a.w * w3);
  }
}

// ---------------------------------------------------------------------------
// Kernel 2: big input GEMM  part[kz] += Z(400x32000) @ Wih0^T(32000x1024)
// fp32, 128x128 tile, 8x8 microtile, BK=32, split-K=16 (grid 4x8x16=512 WGs)
// ---------------------------------------------------------------------------
__global__ __launch_bounds__(256, 2) void gemm_ih(
    const float* __restrict__ Z, const float* __restrict__ W,
    float* __restrict__ part) {
  const int mt = blockIdx.x;  // 0..3
  const int nt = blockIdx.y;  // 0..7
  const int kz = blockIdx.z;  // 0..15
  const int k0 = kz * KRANGE_;
  __shared__ float As[32 * 132];
  __shared__ float Bs[32 * 132];
  const int tid = threadIdx.x;
  const int lrow = tid >> 3;       // 0..31
  const int kq = tid & 7;          // k-quad
  const int mi = (tid & 15) * 8;   // micro row base
  const int ni = (tid >> 4) * 8;   // micro col base

  float acc[8][8];
#pragma unroll
  for (int i = 0; i < 8; ++i)
#pragma unroll
    for (int j = 0; j < 8; ++j) acc[i][j] = 0.f;

  for (int it = 0; it < 63; ++it) {
    const int kb = k0 + it * 32;
#pragma unroll
    for (int p = 0; p < 4; ++p) {
      const int rl = lrow + p * 32;
      const int gk = kb + kq * 4;
      const bool kok = (gk + 4) <= (k0 + KRANGE_);
      const int gr = mt * 128 + rl;
      float4 va = make_float4(0.f, 0.f, 0.f, 0.f);
      if (kok && gr < R_) va = *(const float4*)(Z + (size_t)gr * K0_ + gk);
      As[(kq * 4 + 0) * 132 + rl] = va.x;
      As[(kq * 4 + 1) * 132 + rl] = va.y;
      As[(kq * 4 + 2) * 132 + rl] = va.z;
      As[(kq * 4 + 3) * 132 + rl] = va.w;
      const int gn = nt * 128 + rl;
      float4 vb = make_float4(0.f, 0.f, 0.f, 0.f);
      if (kok) vb = *(const float4*)(W + (size_t)gn * K0_ + gk);
      Bs[(kq * 4 + 0) * 132 + rl] = vb.x;
      Bs[(kq * 4 + 1) * 132 + rl] = vb.y;
      Bs[(kq * 4 + 2) * 132 + rl] = vb.z;
      Bs[(kq * 4 + 3) * 132 + rl] = vb.w;
    }
    __syncthreads();
#pragma unroll 4
    for (int kk = 0; kk < 32; ++kk) {
      float avv[8], bvv[8];
      *(float4*)&avv[0] = *(const float4*)&As[kk * 132 + mi];
      *(float4*)&avv[4] = *(const float4*)&As[kk * 132 + mi + 4];
      *(float4*)&bvv[0] = *(const float4*)&Bs[kk * 132 + ni];
      *(float4*)&bvv[4] = *(const float4*)&Bs[kk * 132 + ni + 4];
#pragma unroll
      for (int i = 0; i < 8; ++i)
#pragma unroll
        for (int j = 0; j < 8; ++j) acc[i][j] += avv[i] * bvv[j];
    }
    __syncthreads();
  }
#pragma unroll
  for (int i = 0; i < 8; ++i) {
    const int gr = mt * 128 + mi + i;
    if (gr < R_) {
#pragma unroll
      for (int j = 0; j < 8; ++j)
        part[((size_t)kz * R_ + gr) * NG_ + nt * 128 + ni + j] = acc[i][j];
    }
  }
}

// ---------------------------------------------------------------------------
// Kernel 3: reduce split-K partials + input-side biases -> G0[400][1024]
// ---------------------------------------------------------------------------
__global__ __launch_bounds__(256) void reduce_kernel(
    const float* __restrict__ part, const float* __restrict__ bih0,
    const float* __restrict__ bhh0, float* __restrict__ G0) {
  const int idx = blockIdx.x * 256 + threadIdx.x;
  if (idx >= R_ * NG_) return;
  const int n = idx & (NG_ - 1);
  float s = bih0[n] + bhh0[n];
#pragma unroll
  for (int ks = 0; ks < KS_; ++ks) s += part[(size_t)ks * R_ * NG_ + idx];
  G0[idx] = s;
}

// ---------------------------------------------------------------------------
// Kernel 4: persistent 2-layer LSTM recurrence. 64 WGs (all co-resident):
// WGs 0..31 = layer0 (j-slice of 8 across 4 gates), 32..63 = layer1,
// staggered one step. Cross-WG handoff via agent-scope atomics.
// ---------------------------------------------------------------------------
#define WSTR 260  // LDS W row stride (floats), 16B-aligned

__device__ __forceinline__ void wait_cnt(unsigned* p, unsigned want) {
  unsigned tries = 0;
  while (__hip_atomic_load(p, __ATOMIC_ACQUIRE, __HIP_MEMORY_SCOPE_AGENT) < want) {
    __builtin_amdgcn_s_sleep(2);
    if (++tries > (1u << 24)) break;  // bail instead of hanging
  }
}

__global__ __launch_bounds__(256, 1) void recur_kernel(
    const float* __restrict__ G0, const float* __restrict__ Whh0,
    const float* __restrict__ Wih1, const float* __restrict__ Whh1,
    const float* __restrict__ bih1, const float* __restrict__ bhh1,
    float* __restrict__ h1b, float* __restrict__ h2b,
    unsigned* __restrict__ cnt0, unsigned* __restrict__ cnt1) {
  const int wg = blockIdx.x;
  const int tid = threadIdx.x;
  const bool is1 = wg >= 32;
  const int w = is1 ? wg - 32 : wg;
  const int jb = w * 8;
  const int m = tid >> 5;         // batch 0..7
  const int q = (tid >> 3) & 3;   // gate 0..3 (i,f,g,o)
  const int jj = tid & 7;
  const int n = q * 256 + jb + jj;

  __shared__ float Wa[32 * WSTR];
  __shared__ float Wb[32 * WSTR];
  __shared__ float h1s[8 * 256];
  __shared__ float h2s[8 * 256];
  __shared__ float gs[4 * 64];
  __shared__ float cs[64];

  // stage this WG's weight rows once (row ri = q*8+jj <-> global q*256+jb+jj)
  for (int idx = tid; idx < 32 * 256; idx += 256) {
    const int ri = idx >> 8, k = idx & 255;
    const int gr = (ri >> 3) * 256 + jb + (ri & 7);
    if (!is1) {
      Wa[ri * WSTR + k] = Whh0[(size_t)gr * 256 + k];
    } else {
      Wa[ri * WSTR + k] = Wih1[(size_t)gr * 256 + k];
      Wb[ri * WSTR + k] = Whh1[(size_t)gr * 256 + k];
    }
  }
  if (tid < 64) cs[tid] = 0.f;
  const float bias1 = is1 ? (bih1[n] + bhh1[n]) : 0.f;
  __syncthreads();

  const float* warow = &Wa[(q * 8 + jj) * WSTR];
  const float* wbrow = &Wb[(q * 8 + jj) * WSTR];

  for (int t = 0; t < T_; ++t) {
    // ---- acquire inputs ----
    if (tid == 0) {
      if (!is1) {
        if (t > 0) wait_cnt(&cnt0[t - 1], 32);
      } else {
        wait_cnt(&cnt0[t], 32);
        if (t > 0) wait_cnt(&cnt1[t - 1], 32);
      }
    }
    __syncthreads();
    // ---- stage h state (agent-scope relaxed atomics: bypass stale caches) ----
    if (!is1) {
      for (int i = tid; i < 2048; i += 256)
        h1s[i] = __hip_atomic_load(h1b + (size_t)t * 2048 + i, __ATOMIC_RELAXED,
                                   __HIP_MEMORY_SCOPE_AGENT);
    } else {
      for (int i = tid; i < 2048; i += 256) {
        h1s[i] = __hip_atomic_load(h1b + (size_t)(t + 1) * 2048 + i,
                                   __ATOMIC_RELAXED, __HIP_MEMORY_SCOPE_AGENT);
        h2s[i] = __hip_atomic_load(h2b + (size_t)t * 2048 + i, __ATOMIC_RELAXED,
                                   __HIP_MEMORY_SCOPE_AGENT);
      }
    }
    __syncthreads();

    // ---- gate dot products ----
    float acc;
    if (!is1) {
      acc = G0[(size_t)(m * T_ + t) * NG_ + n];
      float a0 = 0.f, a1 = 0.f, a2 = 0.f, a3 = 0.f;
      const float* h = &h1s[m * 256];
#pragma unroll 8
      for (int k = 0; k < 256; k += 4) {
        float4 wv = *(const float4*)&warow[k];
        float4 hv = *(const float4*)&h[k];
        a0 += wv.x * hv.x; a1 += wv.y * hv.y;
        a2 += wv.z * hv.z; a3 += wv.w * hv.w;
      }
      acc += (a0 + a1) + (a2 + a3);
    } else {
      acc = bias1;
      float a0 = 0.f, a1 = 0.f, a2 = 0.f, a3 = 0.f;
      const float* h1p = &h1s[m * 256];
      const float* h2p = &h2s[m * 256];
#pragma unroll 8
      for (int k = 0; k < 256; k += 4) {
        float4 wv = *(const float4*)&warow[k];
        float4 hv = *(const float4*)&h1p[k];
        a0 += wv.x * hv.x; a1 += wv.y * hv.y;
        a2 += wv.z * hv.z; a3 += wv.w * hv.w;
        float4 wv2 = *(const float4*)&wbrow[k];
        float4 hv2 = *(const float4*)&h2p[k];
        a0 += wv2.x * hv2.x; a1 += wv2.y * hv2.y;
        a2 += wv2.z * hv2.z; a3 += wv2.w * hv2.w;
      }
      acc += (a0 + a1) + (a2 + a3);
    }
    gs[q * 64 + m * 8 + jj] = acc;
    __syncthreads();

    // ---- pointwise LSTM cell update (64 threads own (m,j) pairs) ----
    if (tid < 64) {
      const int mm = tid >> 3, j2 = tid & 7;
      const float gi = gs[tid];
      const float gf = gs[64 + tid];
      const float gg = gs[128 + tid];
      const float go = gs[192 + tid];
      float c = sigm(gf) * cs[tid] + sigm(gi) * tanhf(gg);
      cs[tid] = c;
      const float h = sigm(go) * tanhf(c);
      float* ob = is1 ? h2b : h1b;
      __hip_atomic_store(ob + (size_t)(t + 1) * 2048 + mm * 256 + jb + j2, h,
                         __ATOMIC_RELAXED, __HIP_MEMORY_SCOPE_AGENT);
    }
    __syncthreads();
    // ---- release ----
    if (tid == 0) {
      __threadfence();
      __hip_atomic_fetch_add(is1 ? &cnt1[t] : &cnt0[t], 1u, __ATOMIC_RELEASE,
                             __HIP_MEMORY_SCOPE_AGENT);
    }
  }
}

// ---------------------------------------------------------------------------
// Kernel 5: FC head  out[8][20000] = tanh(h2[49]) @ fcW^T + fcb
// ---------------------------------------------------------------------------
__global__ __launch_bounds__(256) void fc_kernel(
    const float* __restrict__ h2last, const float* __restrict__ fcW,
    const float* __restrict__ fcb, float* __restrict__ out) {
  __shared__ float tl[2048];
  const int tid = threadIdx.x;
  for (int i = tid; i < 2048; i += 256) tl[i] = tanhf(h2last[i]);
  __syncthreads();
  const int nidx = blockIdx.x * 256 + tid;
  if (nidx >= S_ * N_ * F_) return;
  float accv[8];
#pragma unroll
  for (int m2 = 0; m2 < 8; ++m2) accv[m2] = 0.f;
  const float* wr = fcW + (size_t)nidx * 256;
  for (int k = 0; k < 256; k += 4) {
    float4 w4 = *(const float4*)(wr + k);
#pragma unroll
    for (int m2 = 0; m2 < 8; ++m2) {
      float4 t4 = *(const float4*)&tl[m2 * 256 + k];
      accv[m2] += w4.x * t4.x + w4.y * t4.y + w4.z * t4.z + w4.w * t4.w;
    }
  }
  const float bv = fcb[nidx];
#pragma unroll
  for (int m2 = 0; m2 < 8; ++m2) out[(size_t)m2 * (S_ * N_ * F_) + nidx] = accv[m2] + bv;
}

// ---------------------------------------------------------------------------
// Launch: workspace layout (floats):
//   Z     @ 0          : 400*32000      = 12,800,000
//   part  @ 12,800,000 : 16*400*1024    =  6,553,600   (also GCN partials: 3.2M)
//   G0    @ 19,353,600 : 400*1024       =    409,600
//   h1b   @ 19,763,200 : 51*2048        =    104,448
//   h2b   @ 19,867,648 : 51*2048        =    104,448
//   flags @ 19,972,096 : 128 uint
// total ~79.9 MB of d_ws
// ---------------------------------------------------------------------------
extern "C" void kernel_launch(void* const* d_in, const int* in_sizes, int n_in,
                              void* d_out, int out_size, void* d_ws, size_t ws_size,
                              hipStream_t stream) {
  const float* x    = (const float*)d_in[0];
  const int*   ei   = (const int*)d_in[1];
  const float* ew   = (const float*)d_in[2];
  const float* Wg   = (const float*)d_in[3];
  const float* bg   = (const float*)d_in[4];
  const float* Wih0 = (const float*)d_in[5];
  const float* Whh0 = (const float*)d_in[6];
  const float* bih0 = (const float*)d_in[7];
  const float* bhh0 = (const float*)d_in[8];
  const float* Wih1 = (const float*)d_in[9];
  const float* Whh1 = (const float*)d_in[10];
  const float* bih1 = (const float*)d_in[11];
  const float* bhh1 = (const float*)d_in[12];
  const float* fcW  = (const float*)d_in[13];
  const float* fcb  = (const float*)d_in[14];
  float* out = (float*)d_out;
  float* ws = (float*)d_ws;

  float* Z    = ws;
  float* part = ws + 12800000;
  float* G0   = ws + 19353600;
  float* h1b  = ws + 19763200;
  float* h2b  = ws + 19867648;
  unsigned* cnt0 = (unsigned*)(ws + 19972096);
  unsigned* cnt1 = cnt0 + 64;

  // zero h-state slot0 + flags every call (ws is re-poisoned by harness)
  hipMemsetAsync(h1b, 0, (size_t)(104448 * 2 + 128) * sizeof(float), stream);

  gcn_scatter<<<R_ * 2, 512, 0, stream>>>(x, ei, ew, part);
  gcn_transform<<<R_, 256, 0, stream>>>(part, Wg, bg, Z);
  gemm_ih<<<dim3(4, 8, KS_), 256, 0, stream>>>(Z, Wih0, part);
  reduce_kernel<<<(R_ * NG_ + 255) / 256, 256, 0, stream>>>(part, bih0, bhh0, G0);
  recur_kernel<<<64, 256, 0, stream>>>(G0, Whh0, Wih1, Whh1, bih1, bhh1, h1b,
                                       h2b, cnt0, cnt1);
  fc_kernel<<<(S_ * N_ * F_ + 255) / 256, 256, 0, stream>>>(h2b + 50 * 2048,
                                                            fcW, fcb, out);
}

// Round 2
// 1218.624 us; speedup vs baseline: 3.2247x; 1.2939x over previous
//
#include <hip/hip_runtime.h>
#include <math.h>

// Problem constants
#define B_ 8
#define T_ 50
#define N_ 1000
#define F_ 4
#define G_ 32
#define H_ 256
#define E_ 32000
#define S_ 5
#define R_ 400        // B*T
#define K0_ 32000     // N*G (LSTM0 input size)
#define NG_ 1024      // 4*H
#define KS_ 16        // split-K factor for big GEMM

typedef unsigned int uint_;
typedef unsigned short ushort_;
typedef __attribute__((ext_vector_type(8))) short bf16x8;
typedef __attribute__((ext_vector_type(4))) float f32x4;

static __device__ __forceinline__ float sigm(float x) { return 1.0f / (1.0f + expf(-x)); }

// bf16 round-to-nearest-even split helpers
static __device__ __forceinline__ ushort_ f2bf(float x) {
  uint_ u = __float_as_uint(x);
  u += 0x7FFFu + ((u >> 16) & 1u);
  return (ushort_)(u >> 16);
}
static __device__ __forceinline__ float bf2f(ushort_ b) {
  return __uint_as_float(((uint_)b) << 16);
}
static __device__ __forceinline__ uint_ pk2(float a, float b) {
  return (uint_)f2bf(a) | ((uint_)f2bf(b) << 16);
}
static __device__ __forceinline__ float resid(float x) {
  return x - bf2f(f2bf(x));
}

// async global->LDS 16B
static __device__ __forceinline__ void gload_lds16(const void* g, void* l) {
  __builtin_amdgcn_global_load_lds(
      (const __attribute__((address_space(1))) uint_*)g,
      (__attribute__((address_space(3))) uint_*)l, 16, 0, 0);
}

// ---------------------------------------------------------------------------
// Kernel 1a: GCN scatter, reassociated as (A @ X) @ W.  (unchanged)
// ---------------------------------------------------------------------------
__global__ __launch_bounds__(512, 8) void gcn_scatter(
    const float* __restrict__ x, const int* __restrict__ ei,
    const float* __restrict__ ew, float* __restrict__ P) {
  __shared__ float xs[N_ * 4];
  __shared__ float aggX[N_ * 4];
  const int r = blockIdx.x >> 1;
  const int eh = blockIdx.x & 1;
  const int tid = threadIdx.x;

  const float4* xg = (const float4*)(x + (size_t)r * N_ * F_);
  float4* xs4 = (float4*)xs;
  for (int i = tid; i < N_; i += 512) xs4[i] = xg[i];
  float4* av = (float4*)aggX;
  for (int i = tid; i < N_; i += 512) av[i] = make_float4(0.f, 0.f, 0.f, 0.f);
  __syncthreads();

  const int* src = ei + (size_t)r * 2 * E_;
  const int* dst = src + E_;
  const float* wp = ew + (size_t)r * E_;

  const int f = tid & 3;
  const int es = tid >> 2;
  const int e0 = eh * (E_ / 2);
  const int e1 = e0 + (E_ / 2);
  for (int e = e0 + es; e < e1; e += 128) {
    const int s = src[e], d = dst[e];
    const float m = wp[e] * xs[(s << 2) | f];
    unsafeAtomicAdd(&aggX[(d << 2) | f], m);
  }
  __syncthreads();

  float4* pv = (float4*)(P + (size_t)blockIdx.x * (N_ * 4));
  for (int i = tid; i < N_; i += 512) pv[i] = av[i];
}

// ---------------------------------------------------------------------------
// Kernel 1b: merge partials; z = tanh(aggX@Wg + b); emit SPLIT bf16 Zh/Zl
// in a per-row granule-permuted layout so gemm's linear global_load_lds +
// XOR-swizzled ds_read_b128 is bank-conflict-free (m173 pattern).
// Layout: row r (swz s=(r>>1)&3), 32-k window n: position-granule p holds
// logical granule p^s.  k = n*32 + g (g = GCN channel).
// ---------------------------------------------------------------------------
__global__ __launch_bounds__(256) void gcn_transform(
    const float* __restrict__ P, const float* __restrict__ Wg,
    const float* __restrict__ bg, ushort_* __restrict__ Zh,
    ushort_* __restrict__ Zl) {
  __shared__ float mm[N_ * 4];
  __shared__ float wg[128];
  __shared__ float bgl[32];
  const int r = blockIdx.x;
  const int tid = threadIdx.x;
  const float* P0 = P + (size_t)(2 * r) * (N_ * 4);
  const float* P1 = P0 + N_ * 4;
  for (int i = tid; i < N_ * 4; i += 256) mm[i] = P0[i] + P1[i];
  if (tid < 128) wg[tid] = Wg[tid];           // Wg is [4][32] row-major
  if (tid < 32) bgl[tid] = bg[tid];
  __syncthreads();

  const int s = (r >> 1) & 3;
  ushort_* zhr = Zh + (size_t)r * K0_;
  ushort_* zlr = Zl + (size_t)r * K0_;
  for (int q = tid; q < 4000; q += 256) {   // granule = 8 consecutive k
    const int n = q >> 2, gb = q & 3;
    const float4 a = *(const float4*)&mm[n << 2];
    float z[8];
#pragma unroll
    for (int j = 0; j < 8; ++j) {
      const int g = gb * 8 + j;
      z[j] = tanhf(bgl[g] + a.x * wg[g] + a.y * wg[32 + g] + a.z * wg[64 + g] +
                   a.w * wg[96 + g]);
    }
    uint4 vh, vl;
    vh.x = pk2(z[0], z[1]); vh.y = pk2(z[2], z[3]);
    vh.z = pk2(z[4], z[5]); vh.w = pk2(z[6], z[7]);
    vl.x = pk2(resid(z[0]), resid(z[1])); vl.y = pk2(resid(z[2]), resid(z[3]));
    vl.z = pk2(resid(z[4]), resid(z[5])); vl.w = pk2(resid(z[6]), resid(z[7]));
    const size_t off = (size_t)n * 32 + ((size_t)(gb ^ s) << 3);
    *(uint4*)&zhr[off] = vh;
    *(uint4*)&zlr[off] = vl;
  }
}

// ---------------------------------------------------------------------------
// Kernel 2: bf16x3 MFMA GEMM: part[kz] = Zh@Wh^T + Zh@Wl^T + Zl@Wh^T (tiles)
// 128x128 tile, 4 waves x (64x64), BK=32, mfma_f32_16x16x32_bf16.
// A (Zh/Zl) staged via global_load_lds (source pre-permuted by transform);
// B (Wih0 fp32) reg-staged + split on the fly + swizzled ds_write_b128.
// Split-K = 16 uneven: kz<8 -> 2016 k (63 steps), else 1984 (62 steps).
// ---------------------------------------------------------------------------
__global__ __launch_bounds__(256, 2) void gemm_x3(
    const ushort_* __restrict__ Zh, const ushort_* __restrict__ Zl,
    const float* __restrict__ W, float* __restrict__ part) {
  const int mt = blockIdx.x;  // 0..3
  const int nt = blockIdx.y;  // 0..7
  const int kz = blockIdx.z;  // 0..15
  const int k0 = (kz < 8) ? kz * 2016 : 16128 + (kz - 8) * 1984;
  const int nsteps = (kz < 8) ? 63 : 62;

  __shared__ __align__(16) ushort_ Ah[128 * 32];
  __shared__ __align__(16) ushort_ Al[128 * 32];
  __shared__ __align__(16) ushort_ Bh[128 * 32];
  __shared__ __align__(16) ushort_ Bl[128 * 32];

  const int tid = threadIdx.x;
  const int lane = tid & 63, wv = tid >> 6;
  const int wr = wv >> 1, wc = wv & 1;

  // A staging: idx = i*256+tid -> LDS byte idx*16; row=idx>>2, pos=idx&3
  const int ar0 = tid >> 2, ap = tid & 3;
  const int ar1 = 64 + (tid >> 2);
  const ushort_* zh0 = Zh + (size_t)(mt * 128 + ar0) * K0_ + k0 + ap * 8;
  const ushort_* zh1 = Zh + (size_t)(mt * 128 + ar1) * K0_ + k0 + ap * 8;
  const ushort_* zl0 = Zl + (size_t)(mt * 128 + ar0) * K0_ + k0 + ap * 8;
  const ushort_* zl1 = Zl + (size_t)(mt * 128 + ar1) * K0_ + k0 + ap * 8;

  // B staging: thread -> (local row bn, k-half bh2): 16 fp32 -> 2 granules
  const int bn = tid >> 1, bh2 = tid & 1;
  const int sB = (bn >> 1) & 3;
  const int q0 = (bh2 * 2) ^ sB, q1 = (bh2 * 2 + 1) ^ sB;
  const float* wrow = W + (size_t)(nt * 128 + bn) * K0_ + k0 + bh2 * 16;

  f32x4 acc[4][4];
#pragma unroll
  for (int i = 0; i < 4; ++i)
#pragma unroll
    for (int j = 0; j < 4; ++j) acc[i][j] = (f32x4){0.f, 0.f, 0.f, 0.f};

  for (int st = 0; st < nsteps; ++st) {
    // ---- A: 4x async 16B direct-to-LDS ----
    gload_lds16(zh0, &Ah[(size_t)tid * 8]);
    gload_lds16(zh1, &Ah[2048 + (size_t)tid * 8]);
    gload_lds16(zl0, &Al[(size_t)tid * 8]);
    gload_lds16(zl1, &Al[2048 + (size_t)tid * 8]);
    zh0 += 32; zh1 += 32; zl0 += 32; zl1 += 32;

    // ---- B: 16 fp32 -> split bf16 -> swizzled LDS ----
    const float4 w0 = *(const float4*)(wrow);
    const float4 w1 = *(const float4*)(wrow + 4);
    const float4 w2 = *(const float4*)(wrow + 8);
    const float4 w3 = *(const float4*)(wrow + 12);
    wrow += 32;
    uint4 ha, hb, la, lb;
    ha.x = pk2(w0.x, w0.y); ha.y = pk2(w0.z, w0.w);
    ha.z = pk2(w1.x, w1.y); ha.w = pk2(w1.z, w1.w);
    la.x = pk2(resid(w0.x), resid(w0.y)); la.y = pk2(resid(w0.z), resid(w0.w));
    la.z = pk2(resid(w1.x), resid(w1.y)); la.w = pk2(resid(w1.z), resid(w1.w));
    hb.x = pk2(w2.x, w2.y); hb.y = pk2(w2.z, w2.w);
    hb.z = pk2(w3.x, w3.y); hb.w = pk2(w3.z, w3.w);
    lb.x = pk2(resid(w2.x), resid(w2.y)); lb.y = pk2(resid(w2.z), resid(w2.w));
    lb.z = pk2(resid(w3.x), resid(w3.y)); lb.w = pk2(resid(w3.z), resid(w3.w));
    *(uint4*)&Bh[bn * 32 + q0 * 8] = ha;
    *(uint4*)&Bh[bn * 32 + q1 * 8] = hb;
    *(uint4*)&Bl[bn * 32 + q0 * 8] = la;
    *(uint4*)&Bl[bn * 32 + q1 * 8] = lb;

    __syncthreads();  // drains vmcnt (gload_lds) + lgkm (ds_write)

    // ---- fragments (XOR-swizzled reads: bank-conflict-free) ----
    bf16x8 afh[4], afl[4], bfh[4], bfl[4];
#pragma unroll
    for (int i = 0; i < 4; ++i) {
      const int arow = wr * 64 + i * 16 + (lane & 15);
      const int aq = (lane >> 4) ^ ((arow >> 1) & 3);
      afh[i] = *(const bf16x8*)&Ah[arow * 32 + aq * 8];
      afl[i] = *(const bf16x8*)&Al[arow * 32 + aq * 8];
      const int brow = wc * 64 + i * 16 + (lane & 15);
      const int bq = (lane >> 4) ^ ((brow >> 1) & 3);
      bfh[i] = *(const bf16x8*)&Bh[brow * 32 + bq * 8];
      bfl[i] = *(const bf16x8*)&Bl[brow * 32 + bq * 8];
    }
    // ---- 48 MFMA: 3 split-products per fragment pair ----
#pragma unroll
    for (int i = 0; i < 4; ++i)
#pragma unroll
      for (int j = 0; j < 4; ++j) {
        acc[i][j] = __builtin_amdgcn_mfma_f32_16x16x32_bf16(afh[i], bfh[j], acc[i][j], 0, 0, 0);
        acc[i][j] = __builtin_amdgcn_mfma_f32_16x16x32_bf16(afh[i], bfl[j], acc[i][j], 0, 0, 0);
        acc[i][j] = __builtin_amdgcn_mfma_f32_16x16x32_bf16(afl[i], bfh[j], acc[i][j], 0, 0, 0);
      }
    __syncthreads();
  }

  // ---- epilogue: C row = (lane>>4)*4+reg, col = lane&15 (m89 layout) ----
  const int crow0 = mt * 128 + wr * 64 + ((lane >> 4) << 2);
  const int ccol = nt * 128 + wc * 64 + (lane & 15);
  float* pbase = part + (size_t)kz * R_ * NG_;
#pragma unroll
  for (int i = 0; i < 4; ++i)
#pragma unroll
    for (int rr = 0; rr < 4; ++rr) {
      const int gr = crow0 + i * 16 + rr;
      if (gr < R_) {
#pragma unroll
        for (int j = 0; j < 4; ++j)
          pbase[(size_t)gr * NG_ + ccol + j * 16] = acc[i][j][rr];
      }
    }
}

// ---------------------------------------------------------------------------
// Kernel 3: reduce split-K partials + input-side biases -> G0[400][1024]
// ---------------------------------------------------------------------------
__global__ __launch_bounds__(256) void reduce_kernel(
    const float* __restrict__ part, const float* __restrict__ bih0,
    const float* __restrict__ bhh0, float* __restrict__ G0) {
  const int idx = blockIdx.x * 256 + threadIdx.x;
  if (idx >= R_ * NG_) return;
  const int n = idx & (NG_ - 1);
  float s = bih0[n] + bhh0[n];
#pragma unroll
  for (int ks = 0; ks < KS_; ++ks) s += part[(size_t)ks * R_ * NG_ + idx];
  G0[idx] = s;
}

// ---------------------------------------------------------------------------
// Kernel 4: persistent 2-layer LSTM recurrence (unchanged).
// ---------------------------------------------------------------------------
#define WSTR 260

__device__ __forceinline__ void wait_cnt(unsigned* p, unsigned want) {
  unsigned tries = 0;
  while (__hip_atomic_load(p, __ATOMIC_ACQUIRE, __HIP_MEMORY_SCOPE_AGENT) < want) {
    __builtin_amdgcn_s_sleep(2);
    if (++tries > (1u << 24)) break;
  }
}

__global__ __launch_bounds__(256, 1) void recur_kernel(
    const float* __restrict__ G0, const float* __restrict__ Whh0,
    const float* __restrict__ Wih1, const float* __restrict__ Whh1,
    const float* __restrict__ bih1, const float* __restrict__ bhh1,
    float* __restrict__ h1b, float* __restrict__ h2b,
    unsigned* __restrict__ cnt0, unsigned* __restrict__ cnt1) {
  const int wg = blockIdx.x;
  const int tid = threadIdx.x;
  const bool is1 = wg >= 32;
  const int w = is1 ? wg - 32 : wg;
  const int jb = w * 8;
  const int m = tid >> 5;
  const int q = (tid >> 3) & 3;
  const int jj = tid & 7;
  const int n = q * 256 + jb + jj;

  __shared__ float Wa[32 * WSTR];
  __shared__ float Wb[32 * WSTR];
  __shared__ float h1s[8 * 256];
  __shared__ float h2s[8 * 256];
  __shared__ float gs[4 * 64];
  __shared__ float cs[64];

  for (int idx = tid; idx < 32 * 256; idx += 256) {
    const int ri = idx >> 8, k = idx & 255;
    const int gr = (ri >> 3) * 256 + jb + (ri & 7);
    if (!is1) {
      Wa[ri * WSTR + k] = Whh0[(size_t)gr * 256 + k];
    } else {
      Wa[ri * WSTR + k] = Wih1[(size_t)gr * 256 + k];
      Wb[ri * WSTR + k] = Whh1[(size_t)gr * 256 + k];
    }
  }
  if (tid < 64) cs[tid] = 0.f;
  const float bias1 = is1 ? (bih1[n] + bhh1[n]) : 0.f;
  __syncthreads();

  const float* warow = &Wa[(q * 8 + jj) * WSTR];
  const float* wbrow = &Wb[(q * 8 + jj) * WSTR];

  for (int t = 0; t < T_; ++t) {
    if (tid == 0) {
      if (!is1) {
        if (t > 0) wait_cnt(&cnt0[t - 1], 32);
      } else {
        wait_cnt(&cnt0[t], 32);
        if (t > 0) wait_cnt(&cnt1[t - 1], 32);
      }
    }
    __syncthreads();
    if (!is1) {
      for (int i = tid; i < 2048; i += 256)
        h1s[i] = __hip_atomic_load(h1b + (size_t)t * 2048 + i, __ATOMIC_RELAXED,
                                   __HIP_MEMORY_SCOPE_AGENT);
    } else {
      for (int i = tid; i < 2048; i += 256) {
        h1s[i] = __hip_atomic_load(h1b + (size_t)(t + 1) * 2048 + i,
                                   __ATOMIC_RELAXED, __HIP_MEMORY_SCOPE_AGENT);
        h2s[i] = __hip_atomic_load(h2b + (size_t)t * 2048 + i, __ATOMIC_RELAXED,
                                   __HIP_MEMORY_SCOPE_AGENT);
      }
    }
    __syncthreads();

    float acc;
    if (!is1) {
      acc = G0[(size_t)(m * T_ + t) * NG_ + n];
      float a0 = 0.f, a1 = 0.f, a2 = 0.f, a3 = 0.f;
      const float* h = &h1s[m * 256];
#pragma unroll 8
      for (int k = 0; k < 256; k += 4) {
        float4 wv = *(const float4*)&warow[k];
        float4 hv = *(const float4*)&h[k];
        a0 += wv.x * hv.x; a1 += wv.y * hv.y;
        a2 += wv.z * hv.z; a3 += wv.w * hv.w;
      }
      acc += (a0 + a1) + (a2 + a3);
    } else {
      acc = bias1;
      float a0 = 0.f, a1 = 0.f, a2 = 0.f, a3 = 0.f;
      const float* h1p = &h1s[m * 256];
      const float* h2p = &h2s[m * 256];
#pragma unroll 8
      for (int k = 0; k < 256; k += 4) {
        float4 wv = *(const float4*)&warow[k];
        float4 hv = *(const float4*)&h1p[k];
        a0 += wv.x * hv.x; a1 += wv.y * hv.y;
        a2 += wv.z * hv.z; a3 += wv.w * hv.w;
        float4 wv2 = *(const float4*)&wbrow[k];
        float4 hv2 = *(const float4*)&h2p[k];
        a0 += wv2.x * hv2.x; a1 += wv2.y * hv2.y;
        a2 += wv2.z * hv2.z; a3 += wv2.w * hv2.w;
      }
      acc += (a0 + a1) + (a2 + a3);
    }
    gs[q * 64 + m * 8 + jj] = acc;
    __syncthreads();

    if (tid < 64) {
      const int mm = tid >> 3, j2 = tid & 7;
      const float gi = gs[tid];
      const float gf = gs[64 + tid];
      const float gg = gs[128 + tid];
      const float go = gs[192 + tid];
      float c = sigm(gf) * cs[tid] + sigm(gi) * tanhf(gg);
      cs[tid] = c;
      const float h = sigm(go) * tanhf(c);
      float* ob = is1 ? h2b : h1b;
      __hip_atomic_store(ob + (size_t)(t + 1) * 2048 + mm * 256 + jb + j2, h,
                         __ATOMIC_RELAXED, __HIP_MEMORY_SCOPE_AGENT);
    }
    __syncthreads();
    if (tid == 0) {
      __threadfence();
      __hip_atomic_fetch_add(is1 ? &cnt1[t] : &cnt0[t], 1u, __ATOMIC_RELEASE,
                             __HIP_MEMORY_SCOPE_AGENT);
    }
  }
}

// ---------------------------------------------------------------------------
// Kernel 5: FC head (unchanged)
// ---------------------------------------------------------------------------
__global__ __launch_bounds__(256) void fc_kernel(
    const float* __restrict__ h2last, const float* __restrict__ fcW,
    const float* __restrict__ fcb, float* __restrict__ out) {
  __shared__ float tl[2048];
  const int tid = threadIdx.x;
  for (int i = tid; i < 2048; i += 256) tl[i] = tanhf(h2last[i]);
  __syncthreads();
  const int nidx = blockIdx.x * 256 + tid;
  if (nidx >= S_ * N_ * F_) return;
  float accv[8];
#pragma unroll
  for (int m2 = 0; m2 < 8; ++m2) accv[m2] = 0.f;
  const float* wr = fcW + (size_t)nidx * 256;
  for (int k = 0; k < 256; k += 4) {
    float4 w4 = *(const float4*)(wr + k);
#pragma unroll
    for (int m2 = 0; m2 < 8; ++m2) {
      float4 t4 = *(const float4*)&tl[m2 * 256 + k];
      accv[m2] += w4.x * t4.x + w4.y * t4.y + w4.z * t4.z + w4.w * t4.w;
    }
  }
  const float bv = fcb[nidx];
#pragma unroll
  for (int m2 = 0; m2 < 8; ++m2) out[(size_t)m2 * (S_ * N_ * F_) + nidx] = accv[m2] + bv;
}

// ---------------------------------------------------------------------------
// Launch: workspace layout (floats):
//   Zh    @ 0          : 400*32000 bf16 = 6,400,000 floats
//   Zl    @ 6,400,000  : 400*32000 bf16 = 6,400,000 floats
//   part  @ 12,800,000 : 16*400*1024    = 6,553,600  (also GCN partials: 3.2M)
//   G0    @ 19,353,600 : 400*1024       =   409,600
//   h1b   @ 19,763,200 : 51*2048        =   104,448
//   h2b   @ 19,867,648 : 51*2048        =   104,448
//   flags @ 19,972,096 : 128 uint
// total ~79.9 MB of d_ws (identical footprint to previous version)
// ---------------------------------------------------------------------------
extern "C" void kernel_launch(void* const* d_in, const int* in_sizes, int n_in,
                              void* d_out, int out_size, void* d_ws, size_t ws_size,
                              hipStream_t stream) {
  const float* x    = (const float*)d_in[0];
  const int*   ei   = (const int*)d_in[1];
  const float* ew   = (const float*)d_in[2];
  const float* Wg   = (const float*)d_in[3];
  const float* bg   = (const float*)d_in[4];
  const float* Wih0 = (const float*)d_in[5];
  const float* Whh0 = (const float*)d_in[6];
  const float* bih0 = (const float*)d_in[7];
  const float* bhh0 = (const float*)d_in[8];
  const float* Wih1 = (const float*)d_in[9];
  const float* Whh1 = (const float*)d_in[10];
  const float* bih1 = (const float*)d_in[11];
  const float* bhh1 = (const float*)d_in[12];
  const float* fcW  = (const float*)d_in[13];
  const float* fcb  = (const float*)d_in[14];
  float* out = (float*)d_out;
  float* ws = (float*)d_ws;

  ushort_* Zh = (ushort_*)ws;
  ushort_* Zl = (ushort_*)(ws + 6400000);
  float* part = ws + 12800000;
  float* G0   = ws + 19353600;
  float* h1b  = ws + 19763200;
  float* h2b  = ws + 19867648;
  unsigned* cnt0 = (unsigned*)(ws + 19972096);
  unsigned* cnt1 = cnt0 + 64;

  // zero h-state slot0 + flags every call (ws is re-poisoned by harness)
  hipMemsetAsync(h1b, 0, (size_t)(104448 * 2 + 128) * sizeof(float), stream);

  gcn_scatter<<<R_ * 2, 512, 0, stream>>>(x, ei, ew, part);
  gcn_transform<<<R_, 256, 0, stream>>>(part, Wg, bg, Zh, Zl);
  gemm_x3<<<dim3(4, 8, KS_), 256, 0, stream>>>(Zh, Zl, Wih0, part);
  reduce_kernel<<<(R_ * NG_ + 255) / 256, 256, 0, stream>>>(part, bih0, bhh0, G0);
  recur_kernel<<<64, 256, 0, stream>>>(G0, Whh0, Wih1, Whh1, bih1, bhh1, h1b,
                                       h2b, cnt0, cnt1);
  fc_kernel<<<(S_ * N_ * F_ + 255) / 256, 256, 0, stream>>>(h2b + 50 * 2048,
                                                            fcW, fcb, out);
}

// Round 3
// 907.991 us; speedup vs baseline: 4.3279x; 1.3421x over previous
//
#include <hip/hip_runtime.h>
#include <math.h>

// Problem constants
#define B_ 8
#define T_ 50
#define N_ 1000
#define F_ 4
#define G_ 32
#define H_ 256
#define E_ 32000
#define S_ 5
#define R_ 400        // B*T
#define K0_ 32000     // N*G (LSTM0 input size)
#define NG_ 1024      // 4*H
#define KS_ 16        // split-K factor for big GEMM

#define L0_WGS 8      // layer0: 8 WGs x 128 gate-rows (j-width 32 per gate)
#define L1_WGS 16     // layer1: 16 WGs x 64 gate-rows (j-width 16 per gate)

typedef unsigned int uint_;
typedef unsigned short ushort_;
typedef unsigned long long u64_;
typedef __attribute__((ext_vector_type(8))) short bf16x8;
typedef __attribute__((ext_vector_type(4))) float f32x4;

static __device__ __forceinline__ float sigm(float x) { return 1.0f / (1.0f + expf(-x)); }

// bf16 round-to-nearest-even split helpers
static __device__ __forceinline__ ushort_ f2bf(float x) {
  uint_ u = __float_as_uint(x);
  u += 0x7FFFu + ((u >> 16) & 1u);
  return (ushort_)(u >> 16);
}
static __device__ __forceinline__ float bf2f(ushort_ b) {
  return __uint_as_float(((uint_)b) << 16);
}
static __device__ __forceinline__ uint_ pk2(float a, float b) {
  return (uint_)f2bf(a) | ((uint_)f2bf(b) << 16);
}
static __device__ __forceinline__ float resid(float x) {
  return x - bf2f(f2bf(x));
}
// split 8 fp32 -> hi/lo bf16x8
static __device__ __forceinline__ void split8(const float* v, bf16x8* hi, bf16x8* lo) {
  bf16x8 h8, l8;
#pragma unroll
  for (int j = 0; j < 8; ++j) {
    ushort_ hb = f2bf(v[j]);
    h8[j] = (short)hb;
    l8[j] = (short)f2bf(v[j] - bf2f(hb));
  }
  *hi = h8; *lo = l8;
}

// async global->LDS 16B
static __device__ __forceinline__ void gload_lds16(const void* g, void* l) {
  __builtin_amdgcn_global_load_lds(
      (const __attribute__((address_space(1))) uint_*)g,
      (__attribute__((address_space(3))) uint_*)l, 16, 0, 0);
}

// ---------------------------------------------------------------------------
// Kernel 1a: GCN scatter, reassociated as (A @ X) @ W.  (unchanged)
// ---------------------------------------------------------------------------
__global__ __launch_bounds__(512, 8) void gcn_scatter(
    const float* __restrict__ x, const int* __restrict__ ei,
    const float* __restrict__ ew, float* __restrict__ P) {
  __shared__ float xs[N_ * 4];
  __shared__ float aggX[N_ * 4];
  const int r = blockIdx.x >> 1;
  const int eh = blockIdx.x & 1;
  const int tid = threadIdx.x;

  const float4* xg = (const float4*)(x + (size_t)r * N_ * F_);
  float4* xs4 = (float4*)xs;
  for (int i = tid; i < N_; i += 512) xs4[i] = xg[i];
  float4* av = (float4*)aggX;
  for (int i = tid; i < N_; i += 512) av[i] = make_float4(0.f, 0.f, 0.f, 0.f);
  __syncthreads();

  const int* src = ei + (size_t)r * 2 * E_;
  const int* dst = src + E_;
  const float* wp = ew + (size_t)r * E_;

  const int f = tid & 3;
  const int es = tid >> 2;
  const int e0 = eh * (E_ / 2);
  const int e1 = e0 + (E_ / 2);
  for (int e = e0 + es; e < e1; e += 128) {
    const int s = src[e], d = dst[e];
    const float m = wp[e] * xs[(s << 2) | f];
    unsafeAtomicAdd(&aggX[(d << 2) | f], m);
  }
  __syncthreads();

  float4* pv = (float4*)(P + (size_t)blockIdx.x * (N_ * 4));
  for (int i = tid; i < N_; i += 512) pv[i] = av[i];
}

// ---------------------------------------------------------------------------
// Kernel 1b: merge partials; emit SPLIT bf16 Zh/Zl pre-permuted (unchanged)
// ---------------------------------------------------------------------------
__global__ __launch_bounds__(256) void gcn_transform(
    const float* __restrict__ P, const float* __restrict__ Wg,
    const float* __restrict__ bg, ushort_* __restrict__ Zh,
    ushort_* __restrict__ Zl) {
  __shared__ float mm[N_ * 4];
  __shared__ float wg[128];
  __shared__ float bgl[32];
  const int r = blockIdx.x;
  const int tid = threadIdx.x;
  const float* P0 = P + (size_t)(2 * r) * (N_ * 4);
  const float* P1 = P0 + N_ * 4;
  for (int i = tid; i < N_ * 4; i += 256) mm[i] = P0[i] + P1[i];
  if (tid < 128) wg[tid] = Wg[tid];
  if (tid < 32) bgl[tid] = bg[tid];
  __syncthreads();

  const int s = (r >> 1) & 3;
  ushort_* zhr = Zh + (size_t)r * K0_;
  ushort_* zlr = Zl + (size_t)r * K0_;
  for (int q = tid; q < 4000; q += 256) {
    const int n = q >> 2, gb = q & 3;
    const float4 a = *(const float4*)&mm[n << 2];
    float z[8];
#pragma unroll
    for (int j = 0; j < 8; ++j) {
      const int g = gb * 8 + j;
      z[j] = tanhf(bgl[g] + a.x * wg[g] + a.y * wg[32 + g] + a.z * wg[64 + g] +
                   a.w * wg[96 + g]);
    }
    uint4 vh, vl;
    vh.x = pk2(z[0], z[1]); vh.y = pk2(z[2], z[3]);
    vh.z = pk2(z[4], z[5]); vh.w = pk2(z[6], z[7]);
    vl.x = pk2(resid(z[0]), resid(z[1])); vl.y = pk2(resid(z[2]), resid(z[3]));
    vl.z = pk2(resid(z[4]), resid(z[5])); vl.w = pk2(resid(z[6]), resid(z[7]));
    const size_t off = (size_t)n * 32 + ((size_t)(gb ^ s) << 3);
    *(uint4*)&zhr[off] = vh;
    *(uint4*)&zlr[off] = vl;
  }
}

// ---------------------------------------------------------------------------
// Kernel 2: bf16x3 MFMA GEMM (unchanged)
// ---------------------------------------------------------------------------
__global__ __launch_bounds__(256, 2) void gemm_x3(
    const ushort_* __restrict__ Zh, const ushort_* __restrict__ Zl,
    const float* __restrict__ W, float* __restrict__ part) {
  const int mt = blockIdx.x;
  const int nt = blockIdx.y;
  const int kz = blockIdx.z;
  const int k0 = (kz < 8) ? kz * 2016 : 16128 + (kz - 8) * 1984;
  const int nsteps = (kz < 8) ? 63 : 62;

  __shared__ __align__(16) ushort_ Ah[128 * 32];
  __shared__ __align__(16) ushort_ Al[128 * 32];
  __shared__ __align__(16) ushort_ Bh[128 * 32];
  __shared__ __align__(16) ushort_ Bl[128 * 32];

  const int tid = threadIdx.x;
  const int lane = tid & 63, wv = tid >> 6;
  const int wr = wv >> 1, wc = wv & 1;

  const int ar0 = tid >> 2, ap = tid & 3;
  const int ar1 = 64 + (tid >> 2);
  const ushort_* zh0 = Zh + (size_t)(mt * 128 + ar0) * K0_ + k0 + ap * 8;
  const ushort_* zh1 = Zh + (size_t)(mt * 128 + ar1) * K0_ + k0 + ap * 8;
  const ushort_* zl0 = Zl + (size_t)(mt * 128 + ar0) * K0_ + k0 + ap * 8;
  const ushort_* zl1 = Zl + (size_t)(mt * 128 + ar1) * K0_ + k0 + ap * 8;

  const int bn = tid >> 1, bh2 = tid & 1;
  const int sB = (bn >> 1) & 3;
  const int q0 = (bh2 * 2) ^ sB, q1 = (bh2 * 2 + 1) ^ sB;
  const float* wrow = W + (size_t)(nt * 128 + bn) * K0_ + k0 + bh2 * 16;

  f32x4 acc[4][4];
#pragma unroll
  for (int i = 0; i < 4; ++i)
#pragma unroll
    for (int j = 0; j < 4; ++j) acc[i][j] = (f32x4){0.f, 0.f, 0.f, 0.f};

  for (int st = 0; st < nsteps; ++st) {
    gload_lds16(zh0, &Ah[(size_t)tid * 8]);
    gload_lds16(zh1, &Ah[2048 + (size_t)tid * 8]);
    gload_lds16(zl0, &Al[(size_t)tid * 8]);
    gload_lds16(zl1, &Al[2048 + (size_t)tid * 8]);
    zh0 += 32; zh1 += 32; zl0 += 32; zl1 += 32;

    const float4 w0 = *(const float4*)(wrow);
    const float4 w1 = *(const float4*)(wrow + 4);
    const float4 w2 = *(const float4*)(wrow + 8);
    const float4 w3 = *(const float4*)(wrow + 12);
    wrow += 32;
    uint4 ha, hb, la, lb;
    ha.x = pk2(w0.x, w0.y); ha.y = pk2(w0.z, w0.w);
    ha.z = pk2(w1.x, w1.y); ha.w = pk2(w1.z, w1.w);
    la.x = pk2(resid(w0.x), resid(w0.y)); la.y = pk2(resid(w0.z), resid(w0.w));
    la.z = pk2(resid(w1.x), resid(w1.y)); la.w = pk2(resid(w1.z), resid(w1.w));
    hb.x = pk2(w2.x, w2.y); hb.y = pk2(w2.z, w2.w);
    hb.z = pk2(w3.x, w3.y); hb.w = pk2(w3.z, w3.w);
    lb.x = pk2(resid(w2.x), resid(w2.y)); lb.y = pk2(resid(w2.z), resid(w2.w));
    lb.z = pk2(resid(w3.x), resid(w3.y)); lb.w = pk2(resid(w3.z), resid(w3.w));
    *(uint4*)&Bh[bn * 32 + q0 * 8] = ha;
    *(uint4*)&Bh[bn * 32 + q1 * 8] = hb;
    *(uint4*)&Bl[bn * 32 + q0 * 8] = la;
    *(uint4*)&Bl[bn * 32 + q1 * 8] = lb;

    __syncthreads();

    bf16x8 afh[4], afl[4], bfh[4], bfl[4];
#pragma unroll
    for (int i = 0; i < 4; ++i) {
      const int arow = wr * 64 + i * 16 + (lane & 15);
      const int aq = (lane >> 4) ^ ((arow >> 1) & 3);
      afh[i] = *(const bf16x8*)&Ah[arow * 32 + aq * 8];
      afl[i] = *(const bf16x8*)&Al[arow * 32 + aq * 8];
      const int brow = wc * 64 + i * 16 + (lane & 15);
      const int bq = (lane >> 4) ^ ((brow >> 1) & 3);
      bfh[i] = *(const bf16x8*)&Bh[brow * 32 + bq * 8];
      bfl[i] = *(const bf16x8*)&Bl[brow * 32 + bq * 8];
    }
#pragma unroll
    for (int i = 0; i < 4; ++i)
#pragma unroll
      for (int j = 0; j < 4; ++j) {
        acc[i][j] = __builtin_amdgcn_mfma_f32_16x16x32_bf16(afh[i], bfh[j], acc[i][j], 0, 0, 0);
        acc[i][j] = __builtin_amdgcn_mfma_f32_16x16x32_bf16(afh[i], bfl[j], acc[i][j], 0, 0, 0);
        acc[i][j] = __builtin_amdgcn_mfma_f32_16x16x32_bf16(afl[i], bfh[j], acc[i][j], 0, 0, 0);
      }
    __syncthreads();
  }

  const int crow0 = mt * 128 + wr * 64 + ((lane >> 4) << 2);
  const int ccol = nt * 128 + wc * 64 + (lane & 15);
  float* pbase = part + (size_t)kz * R_ * NG_;
#pragma unroll
  for (int i = 0; i < 4; ++i)
#pragma unroll
    for (int rr = 0; rr < 4; ++rr) {
      const int gr = crow0 + i * 16 + rr;
      if (gr < R_) {
#pragma unroll
        for (int j = 0; j < 4; ++j)
          pbase[(size_t)gr * NG_ + ccol + j * 16] = acc[i][j][rr];
      }
    }
}

// ---------------------------------------------------------------------------
// Kernel 3: reduce split-K partials + input-side biases -> G0[400][1024]
// ---------------------------------------------------------------------------
__global__ __launch_bounds__(256) void reduce_kernel(
    const float* __restrict__ part, const float* __restrict__ bih0,
    const float* __restrict__ bhh0, float* __restrict__ G0) {
  const int idx = blockIdx.x * 256 + threadIdx.x;
  if (idx >= R_ * NG_) return;
  const int n = idx & (NG_ - 1);
  float s = bih0[n] + bhh0[n];
#pragma unroll
  for (int ks = 0; ks < KS_; ++ks) s += part[(size_t)ks * R_ * NG_ + idx];
  G0[idx] = s;
}

// ---------------------------------------------------------------------------
// Kernel 4 (NEW): persistent 2-layer LSTM, MFMA recurrence.
// 24 WGs: 0..7 = layer0 (128 gate-rows each, K=256), 8..23 = layer1
// (64 gate-rows each, K=512 concat [h1;h2]).  Weights pre-split to bf16
// hi/lo B-fragments ONCE, resident in 128 VGPRs per wave (constant across
// all 50 steps -> per-step LDS traffic = A-fragments only).
// h handoff = packed u32 (bf16hi|bf16lo) via relaxed agent atomics; gates
// via bf16-x3 MFMA accumulating fp32; c-state fp32 in LDS.
// ---------------------------------------------------------------------------
__device__ __forceinline__ void wait_cnt_rlx(unsigned* p, unsigned want) {
  unsigned tries = 0;
  while (__hip_atomic_load(p, __ATOMIC_RELAXED, __HIP_MEMORY_SCOPE_AGENT) < want) {
    __builtin_amdgcn_s_sleep(1);
    if (++tries > (1u << 24)) break;  // bail instead of hanging
  }
}

__global__ __launch_bounds__(256, 1) void recur2(
    const float* __restrict__ G0, const float* __restrict__ Whh0,
    const float* __restrict__ Wih1, const float* __restrict__ Whh1,
    const float* __restrict__ bih1, const float* __restrict__ bhh1,
    uint_* __restrict__ h1p, uint_* __restrict__ h2p, float* __restrict__ h2f,
    unsigned* __restrict__ cnt0, unsigned* __restrict__ cnt1) {
  const int wg = blockIdx.x;
  const int tid = threadIdx.x;
  const bool is1 = wg >= L0_WGS;
  const int w = is1 ? wg - L0_WGS : wg;
  const int lane = tid & 63;
  const int wv = tid >> 6;  // wave id == gate q

  // A-fragment buffers: [kstep][lane][8 bf16]; L0 uses first 8 ksteps
  __shared__ __align__(16) ushort_ AfH[16 * 64 * 8];  // 16 KB
  __shared__ __align__(16) ushort_ AfL[16 * 64 * 8];  // 16 KB
  __shared__ float gates[4 * 8 * 32];                 // L0: [q][m][32]; L1: [q][m][16]
  __shared__ float cs[256];                           // c-state (L0 256, L1 128 cells)

  // ---- B-fragment preload (once; constant over t) ----
  bf16x8 BH[16], BL[16];  // L0: [nt2*8+s] (2 ntiles x 8 ksteps); L1: [s] (16 ksteps)
  if (!is1) {
#pragma unroll
    for (int nt2 = 0; nt2 < 2; ++nt2) {
      const int n = wv * 256 + w * 32 + nt2 * 16 + (lane & 15);
      const float* wr = Whh0 + (size_t)n * 256 + (lane >> 4) * 8;
#pragma unroll
      for (int s = 0; s < 8; ++s) {
        float v[8];
        *(float4*)&v[0] = *(const float4*)(wr + s * 32);
        *(float4*)&v[4] = *(const float4*)(wr + s * 32 + 4);
        split8(v, &BH[nt2 * 8 + s], &BL[nt2 * 8 + s]);
      }
    }
  } else {
    const int n = wv * 256 + w * 16 + (lane & 15);
    const float* wr1 = Wih1 + (size_t)n * 256 + (lane >> 4) * 8;
    const float* wr2 = Whh1 + (size_t)n * 256 + (lane >> 4) * 8;
#pragma unroll
    for (int s = 0; s < 16; ++s) {
      const float* wr = (s < 8) ? (wr1 + s * 32) : (wr2 + (s - 8) * 32);
      float v[8];
      *(float4*)&v[0] = *(const float4*)wr;
      *(float4*)&v[4] = *(const float4*)(wr + 4);
      split8(v, &BH[s], &BL[s]);
    }
  }

  // zero A-frag buffers (pad rows m>=8 stay zero forever) + c-state
  {
    uint_* a32 = (uint_*)AfH;
    uint_* b32 = (uint_*)AfL;
    for (int i = tid; i < 4096; i += 256) { a32[i] = 0u; b32[i] = 0u; }
    cs[tid] = 0.f;
  }
  float bias1 = 0.f;
  if (is1) {
    const int n = wv * 256 + w * 16 + (lane & 15);
    bias1 = bih1[n] + bhh1[n];
  }
  __syncthreads();

  for (int t = 0; t < T_; ++t) {
    // ---- G0 prefetch (L0) — issue before poll to hide L2 latency ----
    float g0v[2][4];
    if (!is1) {
#pragma unroll
      for (int nt2 = 0; nt2 < 2; ++nt2)
#pragma unroll
        for (int rr = 0; rr < 4; ++rr) {
          const int m = (lane >> 4) * 4 + rr;
          g0v[nt2][rr] = (m < 8)
              ? G0[(size_t)(m * T_ + t) * NG_ + wv * 256 + w * 32 + nt2 * 16 + (lane & 15)]
              : 0.f;
        }
    }
    // ---- acquire inputs (relaxed polls; data loads bypass caches anyway) ----
    if (tid == 0) {
      if (!is1) {
        if (t > 0) wait_cnt_rlx(&cnt0[t - 1], L0_WGS);
      } else {
        wait_cnt_rlx(&cnt0[t], L0_WGS);
        if (t > 0) wait_cnt_rlx(&cnt1[t - 1], L1_WGS);
      }
    }
    __syncthreads();

    // ---- stage h into A-fragments (unpack packed u32 -> bf16 hi/lo) ----
    if (!is1) {
      // 256 chunks of 8 k: m = tid>>5, c8 = tid&31
      const int m = tid >> 5, c8 = tid & 31;
      const u64_* src = (const u64_*)(h1p + (size_t)t * 2048 + m * 256 + c8 * 8);
      u64_ d[4];
#pragma unroll
      for (int p = 0; p < 4; ++p)
        d[p] = __hip_atomic_load(src + p, __ATOMIC_RELAXED, __HIP_MEMORY_SCOPE_AGENT);
      bf16x8 hh, hl;
#pragma unroll
      for (int p = 0; p < 4; ++p) {
        const uint_ v0 = (uint_)d[p], v1 = (uint_)(d[p] >> 32);
        hh[p * 2] = (short)(v0 & 0xffffu); hl[p * 2] = (short)(v0 >> 16);
        hh[p * 2 + 1] = (short)(v1 & 0xffffu); hl[p * 2 + 1] = (short)(v1 >> 16);
      }
      const int s = c8 >> 2, sub = c8 & 3, ln = m + sub * 16;
      *(bf16x8*)&AfH[(s * 64 + ln) * 8] = hh;
      *(bf16x8*)&AfL[(s * 64 + ln) * 8] = hl;
    } else {
      // 512 chunks: 2 per thread; k<256 -> h1[t+1], else h2[t]
#pragma unroll
      for (int cc = 0; cc < 2; ++cc) {
        const int c = tid + cc * 256;
        const int m = c >> 6, c8 = c & 63, k = c8 * 8;
        const uint_* bp = (k < 256) ? (h1p + (size_t)(t + 1) * 2048 + m * 256 + k)
                                    : (h2p + (size_t)t * 2048 + m * 256 + (k - 256));
        const u64_* src = (const u64_*)bp;
        u64_ d[4];
#pragma unroll
        for (int p = 0; p < 4; ++p)
          d[p] = __hip_atomic_load(src + p, __ATOMIC_RELAXED, __HIP_MEMORY_SCOPE_AGENT);
        bf16x8 hh, hl;
#pragma unroll
        for (int p = 0; p < 4; ++p) {
          const uint_ v0 = (uint_)d[p], v1 = (uint_)(d[p] >> 32);
          hh[p * 2] = (short)(v0 & 0xffffu); hl[p * 2] = (short)(v0 >> 16);
          hh[p * 2 + 1] = (short)(v1 & 0xffffu); hl[p * 2 + 1] = (short)(v1 >> 16);
        }
        const int s = c8 >> 2, sub = c8 & 3, ln = m + sub * 16;
        *(bf16x8*)&AfH[(s * 64 + ln) * 8] = hh;
        *(bf16x8*)&AfL[(s * 64 + ln) * 8] = hl;
      }
    }
    __syncthreads();

    // ---- MFMA gates (x3 split: AhBh + AhBl + AlBh) ----
    f32x4 acc0 = (f32x4){0.f, 0.f, 0.f, 0.f};
    f32x4 acc1 = (f32x4){0.f, 0.f, 0.f, 0.f};
    if (!is1) {
#pragma unroll
      for (int s = 0; s < 8; ++s) {
        const bf16x8 ah = *(const bf16x8*)&AfH[(s * 64 + lane) * 8];
        const bf16x8 al = *(const bf16x8*)&AfL[(s * 64 + lane) * 8];
        acc0 = __builtin_amdgcn_mfma_f32_16x16x32_bf16(ah, BH[s], acc0, 0, 0, 0);
        acc0 = __builtin_amdgcn_mfma_f32_16x16x32_bf16(ah, BL[s], acc0, 0, 0, 0);
        acc0 = __builtin_amdgcn_mfma_f32_16x16x32_bf16(al, BH[s], acc0, 0, 0, 0);
        acc1 = __builtin_amdgcn_mfma_f32_16x16x32_bf16(ah, BH[8 + s], acc1, 0, 0, 0);
        acc1 = __builtin_amdgcn_mfma_f32_16x16x32_bf16(ah, BL[8 + s], acc1, 0, 0, 0);
        acc1 = __builtin_amdgcn_mfma_f32_16x16x32_bf16(al, BH[8 + s], acc1, 0, 0, 0);
      }
    } else {
#pragma unroll
      for (int s = 0; s < 16; ++s) {
        const bf16x8 ah = *(const bf16x8*)&AfH[(s * 64 + lane) * 8];
        const bf16x8 al = *(const bf16x8*)&AfL[(s * 64 + lane) * 8];
        acc0 = __builtin_amdgcn_mfma_f32_16x16x32_bf16(ah, BH[s], acc0, 0, 0, 0);
        acc0 = __builtin_amdgcn_mfma_f32_16x16x32_bf16(ah, BL[s], acc0, 0, 0, 0);
        acc0 = __builtin_amdgcn_mfma_f32_16x16x32_bf16(al, BH[s], acc0, 0, 0, 0);
      }
    }

    // ---- epilogue: C(row=m, col=n-local) -> gates LDS ----
    if (!is1) {
#pragma unroll
      for (int rr = 0; rr < 4; ++rr) {
        const int m = (lane >> 4) * 4 + rr;
        if (m < 8) {
          gates[(wv * 8 + m) * 32 + (lane & 15)] = acc0[rr] + g0v[0][rr];
          gates[(wv * 8 + m) * 32 + 16 + (lane & 15)] = acc1[rr] + g0v[1][rr];
        }
      }
    } else {
#pragma unroll
      for (int rr = 0; rr < 4; ++rr) {
        const int m = (lane >> 4) * 4 + rr;
        if (m < 8) gates[(wv * 8 + m) * 16 + (lane & 15)] = acc0[rr] + bias1;
      }
    }
    __syncthreads();

    // ---- pointwise LSTM cell update + packed h store ----
    if (!is1) {
      const int m = tid >> 5, j = tid & 31;
      const float gi = gates[(0 * 8 + m) * 32 + j];
      const float gf = gates[(1 * 8 + m) * 32 + j];
      const float gg = gates[(2 * 8 + m) * 32 + j];
      const float go = gates[(3 * 8 + m) * 32 + j];
      float c = sigm(gf) * cs[tid] + sigm(gi) * tanhf(gg);
      cs[tid] = c;
      const float h = sigm(go) * tanhf(c);
      const ushort_ hh = f2bf(h);
      const ushort_ hl = f2bf(h - bf2f(hh));
      __hip_atomic_store(h1p + (size_t)(t + 1) * 2048 + m * 256 + w * 32 + j,
                         (uint_)hh | ((uint_)hl << 16), __ATOMIC_RELAXED,
                         __HIP_MEMORY_SCOPE_AGENT);
    } else if (tid < 128) {
      const int m = tid >> 4, j = tid & 15;
      const float gi = gates[(0 * 8 + m) * 16 + j];
      const float gf = gates[(1 * 8 + m) * 16 + j];
      const float gg = gates[(2 * 8 + m) * 16 + j];
      const float go = gates[(3 * 8 + m) * 16 + j];
      float c = sigm(gf) * cs[tid] + sigm(gi) * tanhf(gg);
      cs[tid] = c;
      const float h = sigm(go) * tanhf(c);
      const ushort_ hh = f2bf(h);
      const ushort_ hl = f2bf(h - bf2f(hh));
      __hip_atomic_store(h2p + (size_t)(t + 1) * 2048 + m * 256 + w * 16 + j,
                         (uint_)hh | ((uint_)hl << 16), __ATOMIC_RELAXED,
                         __HIP_MEMORY_SCOPE_AGENT);
      if (t == T_ - 1) h2f[m * 256 + w * 16 + j] = h;  // exact fp32 for FC head
    }
    __syncthreads();
    // ---- release (no extra threadfence: release fetch_add orders stores) ----
    if (tid == 0) {
      __hip_atomic_fetch_add(is1 ? &cnt1[t] : &cnt0[t], 1u, __ATOMIC_RELEASE,
                             __HIP_MEMORY_SCOPE_AGENT);
    }
  }
}

// ---------------------------------------------------------------------------
// Kernel 5: FC head (unchanged; reads fp32 h2 final state)
// ---------------------------------------------------------------------------
__global__ __launch_bounds__(256) void fc_kernel(
    const float* __restrict__ h2last, const float* __restrict__ fcW,
    const float* __restrict__ fcb, float* __restrict__ out) {
  __shared__ float tl[2048];
  const int tid = threadIdx.x;
  for (int i = tid; i < 2048; i += 256) tl[i] = tanhf(h2last[i]);
  __syncthreads();
  const int nidx = blockIdx.x * 256 + tid;
  if (nidx >= S_ * N_ * F_) return;
  float accv[8];
#pragma unroll
  for (int m2 = 0; m2 < 8; ++m2) accv[m2] = 0.f;
  const float* wr = fcW + (size_t)nidx * 256;
  for (int k = 0; k < 256; k += 4) {
    float4 w4 = *(const float4*)(wr + k);
#pragma unroll
    for (int m2 = 0; m2 < 8; ++m2) {
      float4 t4 = *(const float4*)&tl[m2 * 256 + k];
      accv[m2] += w4.x * t4.x + w4.y * t4.y + w4.z * t4.z + w4.w * t4.w;
    }
  }
  const float bv = fcb[nidx];
#pragma unroll
  for (int m2 = 0; m2 < 8; ++m2) out[(size_t)m2 * (S_ * N_ * F_) + nidx] = accv[m2] + bv;
}

// ---------------------------------------------------------------------------
// Launch: workspace layout (floats):
//   Zh    @ 0          : 400*32000 bf16 = 6,400,000 floats
//   Zl    @ 6,400,000  : 400*32000 bf16 = 6,400,000 floats
//   part  @ 12,800,000 : 16*400*1024    = 6,553,600  (also GCN partials; h2f)
//   G0    @ 19,353,600 : 400*1024       =   409,600
//   h1p   @ 19,763,200 : 51*2048 u32    =   104,448
//   h2p   @ 19,867,648 : 51*2048 u32    =   104,448
//   flags @ 19,972,096 : 128 uint
// ---------------------------------------------------------------------------
extern "C" void kernel_launch(void* const* d_in, const int* in_sizes, int n_in,
                              void* d_out, int out_size, void* d_ws, size_t ws_size,
                              hipStream_t stream) {
  const float* x    = (const float*)d_in[0];
  const int*   ei   = (const int*)d_in[1];
  const float* ew   = (const float*)d_in[2];
  const float* Wg   = (const float*)d_in[3];
  const float* bg   = (const float*)d_in[4];
  const float* Wih0 = (const float*)d_in[5];
  const float* Whh0 = (const float*)d_in[6];
  const float* bih0 = (const float*)d_in[7];
  const float* bhh0 = (const float*)d_in[8];
  const float* Wih1 = (const float*)d_in[9];
  const float* Whh1 = (const float*)d_in[10];
  const float* bih1 = (const float*)d_in[11];
  const float* bhh1 = (const float*)d_in[12];
  const float* fcW  = (const float*)d_in[13];
  const float* fcb  = (const float*)d_in[14];
  float* out = (float*)d_out;
  float* ws = (float*)d_ws;

  ushort_* Zh = (ushort_*)ws;
  ushort_* Zl = (ushort_*)(ws + 6400000);
  float* part = ws + 12800000;
  float* G0   = ws + 19353600;
  uint_* h1p  = (uint_*)(ws + 19763200);
  uint_* h2p  = (uint_*)(ws + 19867648);
  unsigned* cnt0 = (unsigned*)(ws + 19972096);
  unsigned* cnt1 = cnt0 + 64;
  float* h2f  = part;  // free during recur2; consumed by fc_kernel

  // zero h-state slot0 + flags every call (ws is re-poisoned by harness)
  hipMemsetAsync(h1p, 0, (size_t)(104448 * 2 + 128) * sizeof(float), stream);

  gcn_scatter<<<R_ * 2, 512, 0, stream>>>(x, ei, ew, part);
  gcn_transform<<<R_, 256, 0, stream>>>(part, Wg, bg, Zh, Zl);
  gemm_x3<<<dim3(4, 8, KS_), 256, 0, stream>>>(Zh, Zl, Wih0, part);
  reduce_kernel<<<(R_ * NG_ + 255) / 256, 256, 0, stream>>>(part, bih0, bhh0, G0);
  recur2<<<L0_WGS + L1_WGS, 256, 0, stream>>>(G0, Whh0, Wih1, Whh1, bih1, bhh1,
                                              h1p, h2p, h2f, cnt0, cnt1);
  fc_kernel<<<(S_ * N_ * F_ + 255) / 256, 256, 0, stream>>>(h2f, fcW, fcb, out);
}